// Round 1
// baseline (281.397 us; speedup 1.0000x reference)
//
#include <hip/hip_runtime.h>
#include <hip/hip_bf16.h>

#define BS 8
#define NH 4
#define NSEQ 2048
#define FIN 64
#define FOUT 32
#define BHH (BS*NH)
#define LOG2E 1.44269504088896340736f

typedef float f32x4 __attribute__((ext_vector_type(4)));

// ---- small scratch in d_ws (float offsets) ----
#define WSS_SE    0
#define WSS_DE    (WSS_SE + BHH*NSEQ)
#define WSS_DS    (WSS_DE + BHH*NSEQ)            // sorted d' per (b,h)
#define WSS_SUFPS (WSS_DS + BHH*NSEQ)            // [BHH][NSEQ+1] scalar suffix sums of 2^d'
#define WSS_PRENS (WSS_SUFPS + BHH*(NSEQ+1))     // [BHH][NSEQ+1] scalar prefix sums of 2^(0.2 d')
#define WSS_INVL  (WSS_PRENS + BHH*(NSEQ+1))     // [BHH][NSEQ] 1/denominator per row
#define WSS_TOTAL (WSS_INVL + BHH*NSEQ)          // = 393280 floats = 1.57 MB

// ---- big scratch in tail of d_out's attn region (float offsets) ----
#define BIG_HP    0                               // [BHH][NSEQ][FOUT]
#define BIG_SUFP  (BIG_HP + BHH*NSEQ*FOUT)        // [BHH][NSEQ+1][FOUT]
#define BIG_PREN  (BIG_SUFP + BHH*(NSEQ+1)*FOUT)  // [BHH][NSEQ+1][FOUT]
#define BIG_TOTAL (BIG_PREN + BHH*(NSEQ+1)*FOUT)  // = 6,293,504 floats (25 MB) << attn (134M floats)

// K1: h_prime = h @ w per head; s = hp.a_src, d = hp.a_dst (scaled by log2 e)
__global__ __launch_bounds__(256) void k1_proj(
    const float* __restrict__ h, const float* __restrict__ w,
    const float* __restrict__ asrc, const float* __restrict__ adst,
    float* __restrict__ ws, float* __restrict__ big)
{
    __shared__ float hl[64*65];                  // 64 rows x 64 feat, pad 65 (2-way free)
    const int b  = blockIdx.x >> 5;
    const int i0 = (blockIdx.x & 31) * 64;
    const int tid = threadIdx.x;
    const float* hsrc = h + ((size_t)b*NSEQ + i0)*FIN;
    for (int x = tid; x < 64*64; x += 256) hl[(x>>6)*65 + (x&63)] = hsrc[x];
    __syncthreads();
    const int head = __builtin_amdgcn_readfirstlane(tid >> 6);  // wave == head
    const int r = tid & 63;
    const int i = i0 + r;
    float acc[FOUT];
#pragma unroll
    for (int o=0;o<FOUT;o++) acc[o]=0.f;
    const float* wh = w + head*FIN*FOUT;         // uniform -> scalar loads
    for (int f=0; f<FIN; f++) {
        const float hv = hl[r*65+f];
#pragma unroll
        for (int o=0;o<FOUT;o++) acc[o] += hv * wh[f*FOUT+o];
    }
    const float* as = asrc + head*FOUT;
    const float* ad = adst + head*FOUT;
    float s=0.f, d=0.f;
#pragma unroll
    for (int o=0;o<FOUT;o++){ s += acc[o]*as[o]; d += acc[o]*ad[o]; }
    const int bh = b*NH + head;
    float* hp = big + BIG_HP + ((size_t)bh*NSEQ + i)*FOUT;
#pragma unroll
    for (int o=0;o<FOUT;o+=4) { f32x4 v = {acc[o],acc[o+1],acc[o+2],acc[o+3]}; *(f32x4*)(hp+o)=v; }
    ws[WSS_SE + bh*NSEQ + i] = s * LOG2E;
    ws[WSS_DE + bh*NSEQ + i] = d * LOG2E;
}

// K2: per (b,h): bitonic sort d'; suffix-scan of 2^d'*hp and prefix-scan of 2^(0.2d')*hp
__global__ __launch_bounds__(1024) void k2_sort_scan(
    float* __restrict__ ws, float* __restrict__ big)
{
    __shared__ float key[NSEQ];
    __shared__ int   sidx[NSEQ];
    __shared__ float totP[16][34];
    __shared__ float totN[16][34];
    const int bh = blockIdx.x;
    const int tid = threadIdx.x;
    for (int x = tid; x < NSEQ; x += 1024) { key[x] = ws[WSS_DE + bh*NSEQ + x]; sidx[x] = x; }
    __syncthreads();
    // bitonic sort ascending, 1024 pairs/substage, 1 pair/thread
    for (int size=2; size<=NSEQ; size<<=1) {
        for (int stride=size>>1; stride>0; stride>>=1) {
            const int p  = tid;
            const int lo = ((p & ~(stride-1)) << 1) | (p & (stride-1));
            const int hi = lo + stride;
            const bool asc = ((lo & size) == 0);
            const float a = key[lo], c = key[hi];
            const bool sw = asc ? (a > c) : (a < c);
            if (sw) { key[lo]=c; key[hi]=a; int t2=sidx[lo]; sidx[lo]=sidx[hi]; sidx[hi]=t2; }
            __syncthreads();
        }
    }
    for (int x = tid; x < NSEQ; x += 1024) ws[WSS_DS + bh*NSEQ + x] = key[x];

    // chunked scans: 16 waves x 128 ranks; lanes 0..31 = hp channels, lane 32 = scalar
    const int wv = tid >> 6, lane = tid & 63;
    const int start = wv*128, end = start+128;
    const float* hpb = big + BIG_HP + (size_t)bh*NSEQ*FOUT;
    float aP=0.f, aN=0.f;
#pragma unroll 4
    for (int r=start; r<end; r++) {
        const float dk = key[r];
        const float wP = __builtin_amdgcn_exp2f(dk);
        const float wN = __builtin_amdgcn_exp2f(0.2f*dk);
        if (lane < FOUT) {
            const float v = hpb[sidx[r]*FOUT + lane];
            aP += wP*v; aN += wN*v;
        } else if (lane == FOUT) { aP += wP; aN += wN; }
    }
    if (lane <= FOUT) { totP[wv][lane] = aP; totN[wv][lane] = aN; }
    __syncthreads();
    float offP=0.f, offN=0.f;
    if (lane <= FOUT) {
#pragma unroll
        for (int c=0;c<16;c++) { if (c>wv) offP += totP[c][lane]; if (c<wv) offN += totN[c][lane]; }
    }
    // suffix: SufP[k] = sum_{r>=k} 2^d'_r * hp[perm r]  (store after add)
    float acc = offP;
#pragma unroll 4
    for (int r=end-1; r>=start; r--) {
        const float wP = __builtin_amdgcn_exp2f(key[r]);
        if (lane < FOUT) {
            acc += wP * hpb[sidx[r]*FOUT + lane];
            big[BIG_SUFP + ((size_t)bh*(NSEQ+1) + r)*FOUT + lane] = acc;
        } else if (lane == FOUT) {
            acc += wP;
            ws[WSS_SUFPS + bh*(NSEQ+1) + r] = acc;
        }
    }
    // prefix: PreN[k] = sum_{r<k} 2^(0.2 d'_r) * hp[perm r]  (store before add)
    acc = offN;
#pragma unroll 4
    for (int r=start; r<end; r++) {
        const float wN = __builtin_amdgcn_exp2f(0.2f*key[r]);
        if (lane < FOUT) {
            big[BIG_PREN + ((size_t)bh*(NSEQ+1) + r)*FOUT + lane] = acc;
            acc += wN * hpb[sidx[r]*FOUT + lane];
        } else if (lane == FOUT) {
            ws[WSS_PRENS + bh*(NSEQ+1) + r] = acc;
            acc += wN;
        }
    }
    // boundaries
    if (tid < FOUT) big[BIG_SUFP + ((size_t)bh*(NSEQ+1) + NSEQ)*FOUT + tid] = 0.f;
    if (tid == FOUT) ws[WSS_SUFPS + bh*(NSEQ+1) + NSEQ] = 0.f;
    if (wv == 15) {
        if (lane < FOUT) big[BIG_PREN + ((size_t)bh*(NSEQ+1) + NSEQ)*FOUT + lane] = acc;
        else if (lane == FOUT) ws[WSS_PRENS + bh*(NSEQ+1) + NSEQ] = acc;
    }
}

// K3a: per row: binary search -> denominator + output row from tables; stash 1/l
__global__ __launch_bounds__(256) void k3a_out(
    float* __restrict__ ws, const float* __restrict__ big,
    const float* __restrict__ bvec, float* __restrict__ outp)
{
    __shared__ float dsrt[NSEQ];
    const int bh = blockIdx.x >> 5;
    const int i0 = (blockIdx.x & 31) * 64;
    const int tid = threadIdx.x;
    for (int x=tid; x<NSEQ; x+=256) dsrt[x] = ws[WSS_DS + bh*NSEQ + x];
    __syncthreads();
    const int wv = tid>>6, lane = tid&63;
    const float bval = (lane < FOUT) ? bvec[lane] : 0.f;
    for (int rr=0; rr<16; rr++) {
        const int i = i0 + wv*16 + rr;
        const float sp = ws[WSS_SE + bh*NSEQ + i];
        const float tau = -sp;
        int lo=0, hi=NSEQ;
        while (lo < hi) { const int mid=(lo+hi)>>1; if (dsrt[mid] < tau) lo=mid+1; else hi=mid; }
        const int k = lo;  // first sorted rank with s'+d' >= 0
        const float e1 = __builtin_amdgcn_exp2f(sp);
        const float e2 = __builtin_amdgcn_exp2f(0.2f*sp);
        const float l = e1*ws[WSS_SUFPS + bh*(NSEQ+1)+k] + e2*ws[WSS_PRENS + bh*(NSEQ+1)+k];
        const float inv = 1.0f / l;
        if (lane == 0) ws[WSS_INVL + bh*NSEQ + i] = inv;
        if (lane < FOUT) {
            const float ov = (e1*big[BIG_SUFP + ((size_t)bh*(NSEQ+1)+k)*FOUT + lane]
                            + e2*big[BIG_PREN + ((size_t)bh*(NSEQ+1)+k)*FOUT + lane]) * inv + bval;
            outp[((size_t)bh*NSEQ + i)*FOUT + lane] = ov;
        }
    }
}

// K3b: stream the full attn matrix (memory-bound): p = 2^max(t,0.2t) * inv_l
__global__ __launch_bounds__(256) void k3b_attn(
    const float* __restrict__ ws, float* __restrict__ attn)
{
    __shared__ float de[NSEQ];
    const int bh = blockIdx.x >> 6;
    const int i0 = (blockIdx.x & 63) * 32;
    const int tid = threadIdx.x;
    for (int x=tid; x<NSEQ; x+=256) de[x] = ws[WSS_DE + bh*NSEQ + x];
    __syncthreads();
    const int wv = tid>>6, lane = tid&63;
    for (int rr=0; rr<8; rr++) {
        const int i = i0 + wv*8 + rr;
        const float sp  = ws[WSS_SE   + bh*NSEQ + i];
        const float inv = ws[WSS_INVL + bh*NSEQ + i];
        float* arow = attn + ((size_t)bh*NSEQ + i)*NSEQ;
#pragma unroll
        for (int blk=0; blk<8; blk++) {
            const int j0 = blk*256 + lane*4;
            const f32x4 d4 = *(const f32x4*)&de[j0];
            f32x4 p; float t;
            t = sp + d4.x; p.x = __builtin_amdgcn_exp2f(fmaxf(t, 0.2f*t)) * inv;
            t = sp + d4.y; p.y = __builtin_amdgcn_exp2f(fmaxf(t, 0.2f*t)) * inv;
            t = sp + d4.z; p.z = __builtin_amdgcn_exp2f(fmaxf(t, 0.2f*t)) * inv;
            t = sp + d4.w; p.w = __builtin_amdgcn_exp2f(fmaxf(t, 0.2f*t)) * inv;
            __builtin_nontemporal_store(p, (f32x4*)(arow + j0));
        }
    }
}

extern "C" void kernel_launch(void* const* d_in, const int* in_sizes, int n_in,
                              void* d_out, int out_size, void* d_ws, size_t ws_size,
                              hipStream_t stream)
{
    (void)in_sizes; (void)n_in; (void)out_size; (void)ws_size;
    const float* h    = (const float*)d_in[0];
    const float* w    = (const float*)d_in[1];
    const float* asrc = (const float*)d_in[2];
    const float* adst = (const float*)d_in[3];
    const float* bvec = (const float*)d_in[4];
    float* outp = (float*)d_out;
    float* attn = outp + (size_t)BHH*NSEQ*FOUT;
    // big scratch lives in the TAIL of the attn region; fully read before K3b overwrites it
    float* big  = attn + (size_t)BHH*NSEQ*NSEQ - BIG_TOTAL;
    float* ws   = (float*)d_ws;   // needs 1.57 MB

    k1_proj    <<<BS*32,   256, 0, stream>>>(h, w, asrc, adst, ws, big);
    k2_sort_scan<<<BHH,   1024, 0, stream>>>(ws, big);
    k3a_out    <<<BHH*32,  256, 0, stream>>>(ws, big, bvec, outp);
    k3b_attn   <<<BHH*64,  256, 0, stream>>>(ws, attn);
}

// Round 2
// 261.679 us; speedup vs baseline: 1.0754x; 1.0754x over previous
//
#include <hip/hip_runtime.h>
#include <hip/hip_bf16.h>

#define BS 8
#define NH 4
#define NSEQ 2048
#define FIN 64
#define FOUT 32
#define BHH (BS*NH)
#define NBINS 8192
#define LOG2E 1.44269504088896340736f

typedef float f32x4 __attribute__((ext_vector_type(4)));

// ---- small scratch in d_ws (float offsets) ----
#define WSS_SE    0
#define WSS_DE    (WSS_SE + BHH*NSEQ)
#define WSS_DS    (WSS_DE + BHH*NSEQ)            // sorted d' per (b,h)
#define WSS_SUFPS (WSS_DS + BHH*NSEQ)            // [BHH][NSEQ+1] scalar suffix sums of 2^d'
#define WSS_PRENS (WSS_SUFPS + BHH*(NSEQ+1))     // [BHH][NSEQ+1] scalar prefix sums of 2^(0.2 d')
#define WSS_INVL  (WSS_PRENS + BHH*(NSEQ+1))     // [BHH][NSEQ] 1/denominator per row
#define WSS_TOTAL (WSS_INVL + BHH*NSEQ)          // = 393280 floats = 1.57 MB

// ---- big scratch in tail of d_out's attn region (float offsets) ----
#define BIG_HP    0                               // [BHH][NSEQ][FOUT]
#define BIG_SUFP  (BIG_HP + BHH*NSEQ*FOUT)        // [BHH][NSEQ+1][FOUT]
#define BIG_PREN  (BIG_SUFP + BHH*(NSEQ+1)*FOUT)  // [BHH][NSEQ+1][FOUT]
#define BIG_TOTAL (BIG_PREN + BHH*(NSEQ+1)*FOUT)  // = 6,293,504 floats (25 MB) << attn (134M floats)

// K1: h_prime = h @ w per head; s = hp.a_src, d = hp.a_dst (scaled by log2 e)
__global__ __launch_bounds__(256) void k1_proj(
    const float* __restrict__ h, const float* __restrict__ w,
    const float* __restrict__ asrc, const float* __restrict__ adst,
    float* __restrict__ ws, float* __restrict__ big)
{
    __shared__ float hl[64*65];                  // 64 rows x 64 feat, pad 65 (2-way free)
    const int b  = blockIdx.x >> 5;
    const int i0 = (blockIdx.x & 31) * 64;
    const int tid = threadIdx.x;
    const float* hsrc = h + ((size_t)b*NSEQ + i0)*FIN;
    for (int x = tid; x < 64*64; x += 256) hl[(x>>6)*65 + (x&63)] = hsrc[x];
    __syncthreads();
    const int head = __builtin_amdgcn_readfirstlane(tid >> 6);  // wave == head
    const int r = tid & 63;
    const int i = i0 + r;
    float acc[FOUT];
#pragma unroll
    for (int o=0;o<FOUT;o++) acc[o]=0.f;
    const float* wh = w + head*FIN*FOUT;         // uniform -> scalar loads
    for (int f=0; f<FIN; f++) {
        const float hv = hl[r*65+f];
#pragma unroll
        for (int o=0;o<FOUT;o++) acc[o] += hv * wh[f*FOUT+o];
    }
    const float* as = asrc + head*FOUT;
    const float* ad = adst + head*FOUT;
    float s=0.f, d=0.f;
#pragma unroll
    for (int o=0;o<FOUT;o++){ s += acc[o]*as[o]; d += acc[o]*ad[o]; }
    const int bh = b*NH + head;
    float* hp = big + BIG_HP + ((size_t)bh*NSEQ + i)*FOUT;
#pragma unroll
    for (int o=0;o<FOUT;o+=4) { f32x4 v = {acc[o],acc[o+1],acc[o+2],acc[o+3]}; *(f32x4*)(hp+o)=v; }
    ws[WSS_SE + bh*NSEQ + i] = s * LOG2E;
    ws[WSS_DE + bh*NSEQ + i] = d * LOG2E;
}

// K2: per (b,h): counting-sort d' (8192 bins); suffix-scan of 2^d'*hp, prefix-scan of 2^(0.2d')*hp
__global__ __launch_bounds__(1024) void k2_sort_scan(
    float* __restrict__ ws, float* __restrict__ big)
{
    __shared__ float kin[NSEQ];
    __shared__ float key[NSEQ];
    __shared__ int   sidx[NSEQ];
    __shared__ int   hist[NBINS];
    __shared__ int   wtot[16];
    __shared__ float rmin[16], rmax[16];
    __shared__ float sMin, sInvW;
    __shared__ float totP[16][34];
    __shared__ float totN[16][34];
    const int bh = blockIdx.x;
    const int tid = threadIdx.x;
    const int wv = tid >> 6, lane = tid & 63;

    // load + min/max
    const float x0 = ws[WSS_DE + bh*NSEQ + tid];
    const float x1 = ws[WSS_DE + bh*NSEQ + tid + 1024];
    kin[tid] = x0; kin[tid+1024] = x1;
    float mn = fminf(x0,x1), mx = fmaxf(x0,x1);
#pragma unroll
    for (int off=32; off; off>>=1) {
        mn = fminf(mn, __shfl_xor(mn, off));
        mx = fmaxf(mx, __shfl_xor(mx, off));
    }
    if (lane==0){ rmin[wv]=mn; rmax[wv]=mx; }
    for (int b=tid; b<NBINS; b+=1024) hist[b]=0;
    __syncthreads();
    if (tid==0){
        float a=rmin[0], b2=rmax[0];
        for (int k=1;k<16;k++){ a=fminf(a,rmin[k]); b2=fmaxf(b2,rmax[k]); }
        sMin = a;
        sInvW = (float)NBINS / (b2 - a + 1e-6f);
    }
    __syncthreads();
    const float smin = sMin, sinv = sInvW;
    int b0 = (int)((x0 - smin)*sinv); b0 = b0 > NBINS-1 ? NBINS-1 : (b0 < 0 ? 0 : b0);
    int b1 = (int)((x1 - smin)*sinv); b1 = b1 > NBINS-1 ? NBINS-1 : (b1 < 0 ? 0 : b1);
    atomicAdd(&hist[b0],1); atomicAdd(&hist[b1],1);
    __syncthreads();
    // exclusive scan of hist (8 bins/thread, wave shfl scan, serial 16 wave-totals)
    int loc[8]; int tsum=0;
#pragma unroll
    for (int k=0;k<8;k++){ loc[k]=tsum; tsum += hist[tid*8+k]; }
    int inc = tsum;
#pragma unroll
    for (int off=1; off<64; off<<=1){ int v=__shfl_up(inc,off); if (lane>=off) inc+=v; }
    if (lane==63) wtot[wv]=inc;
    const int laneex = inc - tsum;
    __syncthreads();
    if (tid==0){ int a=0; for (int k=0;k<16;k++){ int v=wtot[k]; wtot[k]=a; a+=v; } }
    __syncthreads();
    const int base = wtot[wv] + laneex;
#pragma unroll
    for (int k=0;k<8;k++) hist[tid*8+k] = base + loc[k];
    __syncthreads();
    // scatter (within-bin order arbitrary; bin width ~5e-4 in log2 domain -> negligible)
    {
        int p0 = atomicAdd(&hist[b0],1); key[p0]=x0; sidx[p0]=tid;
        int p1 = atomicAdd(&hist[b1],1); key[p1]=x1; sidx[p1]=tid+1024;
    }
    __syncthreads();
    for (int x = tid; x < NSEQ; x += 1024) ws[WSS_DS + bh*NSEQ + x] = key[x];

    // chunked scans: 16 waves x 128 ranks; lanes 0..31 = hp channels, lane 32 = scalar
    const int start = wv*128, end = start+128;
    const float* hpb = big + BIG_HP + (size_t)bh*NSEQ*FOUT;
    float aP=0.f, aN=0.f;
#pragma unroll 4
    for (int r=start; r<end; r++) {
        const float dk = key[r];
        const float wP = __builtin_amdgcn_exp2f(dk);
        const float wN = __builtin_amdgcn_exp2f(0.2f*dk);
        if (lane < FOUT) {
            const float v = hpb[sidx[r]*FOUT + lane];
            aP += wP*v; aN += wN*v;
        } else if (lane == FOUT) { aP += wP; aN += wN; }
    }
    if (lane <= FOUT) { totP[wv][lane] = aP; totN[wv][lane] = aN; }
    __syncthreads();
    float offP=0.f, offN=0.f;
    if (lane <= FOUT) {
#pragma unroll
        for (int c=0;c<16;c++) { if (c>wv) offP += totP[c][lane]; if (c<wv) offN += totN[c][lane]; }
    }
    // suffix: SufP[k] = sum_{r>=k} 2^d'_r * hp[perm r]  (store after add)
    float acc = offP;
#pragma unroll 4
    for (int r=end-1; r>=start; r--) {
        const float wP = __builtin_amdgcn_exp2f(key[r]);
        if (lane < FOUT) {
            acc += wP * hpb[sidx[r]*FOUT + lane];
            big[BIG_SUFP + ((size_t)bh*(NSEQ+1) + r)*FOUT + lane] = acc;
        } else if (lane == FOUT) {
            acc += wP;
            ws[WSS_SUFPS + bh*(NSEQ+1) + r] = acc;
        }
    }
    // prefix: PreN[k] = sum_{r<k} 2^(0.2 d'_r) * hp[perm r]  (store before add)
    acc = offN;
#pragma unroll 4
    for (int r=start; r<end; r++) {
        const float wN = __builtin_amdgcn_exp2f(0.2f*key[r]);
        if (lane < FOUT) {
            big[BIG_PREN + ((size_t)bh*(NSEQ+1) + r)*FOUT + lane] = acc;
            acc += wN * hpb[sidx[r]*FOUT + lane];
        } else if (lane == FOUT) {
            ws[WSS_PRENS + bh*(NSEQ+1) + r] = acc;
            acc += wN;
        }
    }
    // boundaries
    if (tid < FOUT) big[BIG_SUFP + ((size_t)bh*(NSEQ+1) + NSEQ)*FOUT + tid] = 0.f;
    if (tid == FOUT) ws[WSS_SUFPS + bh*(NSEQ+1) + NSEQ] = 0.f;
    if (wv == 15) {
        if (lane < FOUT) big[BIG_PREN + ((size_t)bh*(NSEQ+1) + NSEQ)*FOUT + lane] = acc;
        else if (lane == FOUT) ws[WSS_PRENS + bh*(NSEQ+1) + NSEQ] = acc;
    }
}

// K3a: per row: binary search -> denominator + output row from tables; stash 1/l
__global__ __launch_bounds__(256) void k3a_out(
    float* __restrict__ ws, const float* __restrict__ big,
    const float* __restrict__ bvec, float* __restrict__ outp)
{
    __shared__ float dsrt[NSEQ];
    const int bh = blockIdx.x >> 5;
    const int i0 = (blockIdx.x & 31) * 64;
    const int tid = threadIdx.x;
    for (int x=tid; x<NSEQ; x+=256) dsrt[x] = ws[WSS_DS + bh*NSEQ + x];
    __syncthreads();
    const int wv = tid>>6, lane = tid&63;
    const float bval = (lane < FOUT) ? bvec[lane] : 0.f;
    for (int rr=0; rr<16; rr++) {
        const int i = i0 + wv*16 + rr;
        const float sp = ws[WSS_SE + bh*NSEQ + i];
        const float tau = -sp;
        int lo=0, hi=NSEQ;
        while (lo < hi) { const int mid=(lo+hi)>>1; if (dsrt[mid] < tau) lo=mid+1; else hi=mid; }
        const int k = lo;  // first sorted rank with s'+d' >= 0
        const float e1 = __builtin_amdgcn_exp2f(sp);
        const float e2 = __builtin_amdgcn_exp2f(0.2f*sp);
        const float l = e1*ws[WSS_SUFPS + bh*(NSEQ+1)+k] + e2*ws[WSS_PRENS + bh*(NSEQ+1)+k];
        const float inv = 1.0f / l;
        if (lane == 0) ws[WSS_INVL + bh*NSEQ + i] = inv;
        if (lane < FOUT) {
            const float ov = (e1*big[BIG_SUFP + ((size_t)bh*(NSEQ+1)+k)*FOUT + lane]
                            + e2*big[BIG_PREN + ((size_t)bh*(NSEQ+1)+k)*FOUT + lane]) * inv + bval;
            outp[((size_t)bh*NSEQ + i)*FOUT + lane] = ov;
        }
    }
}

// K3b: stream the full attn matrix (memory-bound): p = 2^max(t,0.2t) * inv_l
// plain stores (NOT nontemporal) -- L2 write-combining streams at ~6.7 TB/s like the fill kernels
__global__ __launch_bounds__(256) void k3b_attn(
    const float* __restrict__ ws, float* __restrict__ attn)
{
    __shared__ float de[NSEQ];
    const int bh = blockIdx.x >> 6;
    const int i0 = (blockIdx.x & 63) * 32;
    const int tid = threadIdx.x;
    for (int x=tid; x<NSEQ; x+=256) de[x] = ws[WSS_DE + bh*NSEQ + x];
    __syncthreads();
    const int wv = tid>>6, lane = tid&63;
    for (int rr=0; rr<8; rr++) {
        const int i = i0 + wv*8 + rr;
        const float sp  = ws[WSS_SE   + bh*NSEQ + i];
        const float inv = ws[WSS_INVL + bh*NSEQ + i];
        float* arow = attn + ((size_t)bh*NSEQ + i)*NSEQ;
#pragma unroll
        for (int blk=0; blk<8; blk++) {
            const int j0 = blk*256 + lane*4;
            const f32x4 d4 = *(const f32x4*)&de[j0];
            f32x4 p; float t;
            t = sp + d4.x; p.x = __builtin_amdgcn_exp2f(fmaxf(t, 0.2f*t)) * inv;
            t = sp + d4.y; p.y = __builtin_amdgcn_exp2f(fmaxf(t, 0.2f*t)) * inv;
            t = sp + d4.z; p.z = __builtin_amdgcn_exp2f(fmaxf(t, 0.2f*t)) * inv;
            t = sp + d4.w; p.w = __builtin_amdgcn_exp2f(fmaxf(t, 0.2f*t)) * inv;
            *(f32x4*)(arow + j0) = p;
        }
    }
}

extern "C" void kernel_launch(void* const* d_in, const int* in_sizes, int n_in,
                              void* d_out, int out_size, void* d_ws, size_t ws_size,
                              hipStream_t stream)
{
    (void)in_sizes; (void)n_in; (void)out_size; (void)ws_size;
    const float* h    = (const float*)d_in[0];
    const float* w    = (const float*)d_in[1];
    const float* asrc = (const float*)d_in[2];
    const float* adst = (const float*)d_in[3];
    const float* bvec = (const float*)d_in[4];
    float* outp = (float*)d_out;
    float* attn = outp + (size_t)BHH*NSEQ*FOUT;
    // big scratch lives in the TAIL of the attn region; fully read before K3b overwrites it
    float* big  = attn + (size_t)BHH*NSEQ*NSEQ - BIG_TOTAL;
    float* ws   = (float*)d_ws;   // needs 1.57 MB

    k1_proj     <<<BS*32,  256, 0, stream>>>(h, w, asrc, adst, ws, big);
    k2_sort_scan<<<BHH,   1024, 0, stream>>>(ws, big);
    k3a_out     <<<BHH*32, 256, 0, stream>>>(ws, big, bvec, outp);
    k3b_attn    <<<BHH*64, 256, 0, stream>>>(ws, attn);
}